// Round 1
// baseline (108.282 us; speedup 1.0000x reference)
//
#include <hip/hip_runtime.h>
#include <math.h>

// ---------------------------------------------------------------------------
// FluxAnomalyPredictionTF: F=3, E=6, H=3, d=2, FF=2048, N=16, T=2046, S=W=1024
// ---------------------------------------------------------------------------

#define NB 16
#define TL 2046
#define SL 1024
#define ED 6

__device__ __forceinline__ float relu_(float a){ return fmaxf(a, 0.f); }
__device__ __forceinline__ float fexp2_(float x){ return __builtin_amdgcn_exp2f(x); }

// ------------------------- prep: weight re-layouts -------------------------
// k64r[f][t][k]  (3*64*8)
// fcc[l][j][16]: [0..5]=f1w row j, [6]=f1b[j], [8..13]=f2w[:,j], rest 0
__global__ __launch_bounds__(256) void prep_kernel(
    const float* __restrict__ k64, const float* __restrict__ f1w,
    const float* __restrict__ f1b, const float* __restrict__ f2w,
    float* __restrict__ k64r, float* __restrict__ fcc)
{
  int tid = blockIdx.x * 256 + threadIdx.x;
  int nt  = gridDim.x * 256;
  for (int i = tid; i < 3*64*8; i += nt){
    int f = i >> 9, r = i & 511, t = r >> 3, k = r & 7;
    k64r[i] = k64[k*192 + f*64 + t];
  }
  for (int i = tid; i < 2*2048*16; i += nt){
    int l = i >> 15, r = i & 32767, j = r >> 4, c = r & 15;
    float v = 0.f;
    if (c < 6)       v = f1w[(l*2048 + j)*6 + c];
    else if (c == 6) v = f1b[l*2048 + j];
    else if (c >= 8 && c < 14) v = f2w[(l*6 + (c-8))*2048 + j];
    fcc[i] = v;
  }
}

// ------------------------------ frontend -----------------------------------
// grid 256 = 16 n * 16 stiles ; 192 threads = 3 waves (wave = feature f)
// thread handles token s = s0 + lane for its feature f.
__global__ __launch_bounds__(192) void frontend_kernel(
  const float* __restrict__ x, const float* __restrict__ k64r,
  const float* __restrict__ b64, const float* __restrict__ k16, const float* __restrict__ b16,
  const float* __restrict__ k8,  const float* __restrict__ b8,
  const float* __restrict__ kw3, const float* __restrict__ bw3,
  const float* __restrict__ km3, const float* __restrict__ bm3,
  const float* __restrict__ kn3, const float* __restrict__ bn3,
  const float* __restrict__ fc1w, const float* __restrict__ fc1b,
  const float* __restrict__ fc2w, const float* __restrict__ fc2b,
  float* __restrict__ seq)
{
  __shared__ float xt[3][200];
  __shared__ float k64s[3*64*8];
  __shared__ float flat_s[64][44];
  __shared__ float h1_s[64][20];
  const int tid  = threadIdx.x;
  const int f    = tid >> 6;
  const int lane = tid & 63;
  const int n    = blockIdx.x >> 4;
  const int s0   = (blockIdx.x & 15) << 6;
  const int s    = s0 + lane;

  for (int i = tid; i < 600; i += 192){
    int ff = i / 200, pos = i - ff*200;
    int xp = 2*s0 - 39 + pos;
    xt[ff][pos] = (xp >= 0 && xp < TL) ? x[(n*TL + xp)*3 + ff] : 0.f;
  }
  for (int i = tid; i < 1536; i += 192) k64s[i] = k64r[i];
  __syncthreads();

  // register x window: xr[i] = x[n][2s-39+i]
  float xr[74];
  {
    const int b = 2*lane;
    #pragma unroll
    for (int i = 0; i < 74; i++) xr[i] = xt[f][b + i];
  }

  // ---- wide: 64-tap, 8 kernels at w=s, plus edge (w=s-1,k=7),(w=s+1,k=0) ----
  float accw[8], acc_e0, acc_e1;
  #pragma unroll
  for (int k = 0; k < 8; k++) accw[k] = b64[k*3 + f];
  acc_e0 = accw[7]; acc_e1 = accw[0];
  {
    const float* kp = &k64s[f*512];
    #pragma unroll
    for (int t = 0; t < 64; t++){
      float4 wa = *(const float4*)(kp + t*8);
      float4 wb = *(const float4*)(kp + t*8 + 4);
      float xm = xr[8 + t];
      accw[0] = fmaf(xm, wa.x, accw[0]);
      accw[1] = fmaf(xm, wa.y, accw[1]);
      accw[2] = fmaf(xm, wa.z, accw[2]);
      accw[3] = fmaf(xm, wa.w, accw[3]);
      accw[4] = fmaf(xm, wb.x, accw[4]);
      accw[5] = fmaf(xm, wb.y, accw[5]);
      accw[6] = fmaf(xm, wb.z, accw[6]);
      accw[7] = fmaf(xm, wb.w, accw[7]);
      acc_e0 = fmaf(xr[6 + t],  wb.w, acc_e0);
      acc_e1 = fmaf(xr[10 + t], wa.x, acc_e1);
    }
  }
  float yw[10];
  yw[0] = (s > 0) ? 5.f*relu_(acc_e0) : 0.f;
  #pragma unroll
  for (int c = 1; c <= 8; c++) yw[c] = 5.f*relu_(accw[c-1]);
  yw[9] = (s < 1023) ? 5.f*relu_(acc_e1) : 0.f;

  // ---- mid: 16-tap ----
  float w16r[16];
  #pragma unroll
  for (int t = 0; t < 16; t++) w16r[t] = k16[f*16 + t];
  const float bb16 = b16[f];
  float ym[10];
  #pragma unroll
  for (int ci = 0; ci < 10; ci++){
    const int b = (ci == 0) ? 54 : ((ci == 9) ? 2 : 8*(ci-1));
    float a = bb16;
    #pragma unroll
    for (int t = 0; t < 16; t++) a = fmaf(xr[b + t], w16r[t], a);
    ym[ci] = relu_(a);
  }
  if (s == 0)    ym[0] = 0.f;
  if (s == 1023) ym[9] = 0.f;

  // ---- nar: 8-tap, max over 4 sub-windows ----
  float w8r[8];
  #pragma unroll
  for (int t = 0; t < 8; t++) w8r[t] = k8[f*8 + t];
  const float bb8 = b8[f];
  float yn[10];
  #pragma unroll
  for (int ci = 0; ci < 10; ci++){
    float m = -3.0e38f;
    #pragma unroll
    for (int j2 = 0; j2 < 4; j2++){
      const int b = (ci == 0) ? (58 + 2*j2)
                  : ((ci == 9) ? (6 + 2*j2)
                               : (4 + 2*(4*(ci-1) + j2)));
      float a = bb8;
      #pragma unroll
      for (int t = 0; t < 8; t++) a = fmaf(xr[b + t], w8r[t], a);
      m = fmaxf(m, a);
    }
    yn[ci] = relu_(m);
  }
  if (s == 0)    yn[0] = 0.f;
  if (s == 1023) yn[9] = 0.f;

  // ---- conv3 + relu + pool2 -> flat ----
  {
    float c0 = kw3[f*3], c1 = kw3[f*3+1], c2 = kw3[f*3+2], bb = bw3[f];
    #pragma unroll
    for (int q = 0; q < 4; q++){
      float z0 = relu_(fmaf(c0, yw[2*q],   fmaf(c1, yw[2*q+1], fmaf(c2, yw[2*q+2], bb))));
      float z1 = relu_(fmaf(c0, yw[2*q+1], fmaf(c1, yw[2*q+2], fmaf(c2, yw[2*q+3], bb))));
      flat_s[lane][q*3 + f] = fmaxf(z0, z1);
    }
  }
  {
    float c0 = km3[f*3], c1 = km3[f*3+1], c2 = km3[f*3+2], bb = bm3[f];
    #pragma unroll
    for (int q = 0; q < 4; q++){
      float z0 = relu_(fmaf(c0, ym[2*q],   fmaf(c1, ym[2*q+1], fmaf(c2, ym[2*q+2], bb))));
      float z1 = relu_(fmaf(c0, ym[2*q+1], fmaf(c1, ym[2*q+2], fmaf(c2, ym[2*q+3], bb))));
      flat_s[lane][12 + q*3 + f] = fmaxf(z0, z1);
    }
  }
  {
    float c0 = kn3[f*3], c1 = kn3[f*3+1], c2 = kn3[f*3+2], bb = bn3[f];
    #pragma unroll
    for (int q = 0; q < 4; q++){
      float z0 = relu_(fmaf(c0, yn[2*q],   fmaf(c1, yn[2*q+1], fmaf(c2, yn[2*q+2], bb))));
      float z1 = relu_(fmaf(c0, yn[2*q+1], fmaf(c1, yn[2*q+2], fmaf(c2, yn[2*q+3], bb))));
      flat_s[lane][24 + q*3 + f] = fmaxf(z0, z1);
    }
  }
  __syncthreads();

  // ---- fc1: wave f computes outputs [6f, 6f+6) ----
  #pragma unroll
  for (int oi = 0; oi < 6; oi++){
    const int o = 6*f + oi;
    float acc = fc1b[o];
    const float4* wrow = (const float4*)(fc1w + o*36);
    const float4* frow = (const float4*)(&flat_s[lane][0]);
    #pragma unroll
    for (int i = 0; i < 9; i++){
      float4 wv = wrow[i], fv = frow[i];
      acc = fmaf(wv.x, fv.x, acc); acc = fmaf(wv.y, fv.y, acc);
      acc = fmaf(wv.z, fv.z, acc); acc = fmaf(wv.w, fv.w, acc);
    }
    h1_s[lane][o] = relu_(acc);
  }
  __syncthreads();

  // ---- fc2: wave f computes e = 2f, 2f+1 ----
  #pragma unroll
  for (int ei = 0; ei < 2; ei++){
    const int e = 2*f + ei;
    float acc = fc2b[e];
    #pragma unroll
    for (int o = 0; o < 18; o++) acc = fmaf(h1_s[lane][o], fc2w[e*18 + o], acc);
    seq[(n*SL + s)*ED + e] = relu_(acc);
  }
}

// ------------------------------ attention ----------------------------------
// grid 768 = 16 n * 3 h * 16 stiles ; 128 threads: 64 rows x 2 t-halves.
// qkv fused (recompute per block); scale*log2(e) folded into K; exp2 softmax.
__global__ __launch_bounds__(128) void attn_kernel(
  const float* __restrict__ seq, const float* __restrict__ inw,
  const float* __restrict__ inb, float* __restrict__ att_out, int layer)
{
  __shared__ float4 kv[1024];
  const int tid = threadIdx.x;
  const int bid = blockIdx.x;
  const int n = bid / 48;
  const int r = bid % 48;
  const int h = r >> 4;
  const int stile = r & 15;
  const float* W = inw + layer*108;
  const float* B = inb + layer*18;
  const int h2 = 2*h;
  const float* seqn = seq + n*SL*ED;
  const float SC = 1.0201265650432017f; // (1/sqrt(2)) * log2(e)

  float wk0[6], wk1[6], wv0[6], wv1[6];
  #pragma unroll
  for (int e = 0; e < 6; e++){
    wk0[e] = W[(6 + h2)*6 + e];  wk1[e] = W[(7 + h2)*6 + e];
    wv0[e] = W[(12 + h2)*6 + e]; wv1[e] = W[(13 + h2)*6 + e];
  }
  const float bk0 = B[6 + h2], bk1 = B[7 + h2], bv0 = B[12 + h2], bv1 = B[13 + h2];

  for (int t = tid; t < 1024; t += 128){
    const float* sr = seqn + t*6;
    float a0 = sr[0], a1 = sr[1], a2 = sr[2], a3 = sr[3], a4 = sr[4], a5 = sr[5];
    float k0 = bk0 + a0*wk0[0] + a1*wk0[1] + a2*wk0[2] + a3*wk0[3] + a4*wk0[4] + a5*wk0[5];
    float k1 = bk1 + a0*wk1[0] + a1*wk1[1] + a2*wk1[2] + a3*wk1[3] + a4*wk1[4] + a5*wk1[5];
    float v0 = bv0 + a0*wv0[0] + a1*wv0[1] + a2*wv0[2] + a3*wv0[3] + a4*wv0[4] + a5*wv0[5];
    float v1 = bv1 + a0*wv1[0] + a1*wv1[1] + a2*wv1[2] + a3*wv1[3] + a4*wv1[4] + a5*wv1[5];
    kv[t] = make_float4(k0*SC, k1*SC, v0, v1);
  }

  const int srow = stile*64 + (tid >> 1);
  const int half = tid & 1;
  float q0, q1;
  {
    const float* sr = seqn + srow*6;
    float a0 = sr[0], a1 = sr[1], a2 = sr[2], a3 = sr[3], a4 = sr[4], a5 = sr[5];
    q0 = B[h2]   + a0*W[h2*6]     + a1*W[h2*6+1]     + a2*W[h2*6+2]     + a3*W[h2*6+3]     + a4*W[h2*6+4]     + a5*W[h2*6+5];
    q1 = B[h2+1] + a0*W[(h2+1)*6] + a1*W[(h2+1)*6+1] + a2*W[(h2+1)*6+2] + a3*W[(h2+1)*6+3] + a4*W[(h2+1)*6+4] + a5*W[(h2+1)*6+5];
  }
  __syncthreads();

  float l = 0.f, o0 = 0.f, o1 = 0.f;
  const int t0 = half * 512;
  #pragma unroll 8
  for (int t = t0; t < t0 + 512; t++){
    float4 K = kv[t];
    float sc = fmaf(q0, K.x, q1*K.y);
    float p  = fexp2_(sc);
    l += p;
    o0 = fmaf(p, K.z, o0);
    o1 = fmaf(p, K.w, o1);
  }
  l  += __shfl_xor(l, 1);
  o0 += __shfl_xor(o0, 1);
  o1 += __shfl_xor(o1, 1);
  if (half == 0){
    float inv = 1.0f / l;
    float* orow = att_out + (n*SL + srow)*ED + h2;
    orow[0] = o0*inv; orow[1] = o1*inv;
  }
}

// --------------------------- out-proj + LN ----------------------------------
__global__ __launch_bounds__(128) void oproj_ln_kernel(
  const float* __restrict__ seq_in, const float* __restrict__ att,
  const float* __restrict__ ow, const float* __restrict__ ob,
  const float* __restrict__ lw, const float* __restrict__ lb,
  float* __restrict__ seq_out, int layer)
{
  const int tok = blockIdx.x*128 + threadIdx.x;
  const float* a = att + tok*6;
  const float* W = ow + layer*36;
  const float* Bo = ob + layer*6;
  float av[6];
  #pragma unroll
  for (int e = 0; e < 6; e++) av[e] = a[e];
  float y[6]; float mu = 0.f;
  #pragma unroll
  for (int e = 0; e < 6; e++){
    float o = Bo[e];
    #pragma unroll
    for (int e2 = 0; e2 < 6; e2++) o = fmaf(av[e2], W[e*6 + e2], o);
    y[e] = seq_in[tok*6 + e] + o;
    mu += y[e];
  }
  mu *= (1.f/6.f);
  float var = 0.f;
  #pragma unroll
  for (int e = 0; e < 6; e++){ float d = y[e] - mu; var = fmaf(d, d, var); }
  var *= (1.f/6.f);
  float rstd = rsqrtf(var + 1e-5f);
  #pragma unroll
  for (int e = 0; e < 6; e++)
    seq_out[tok*6 + e] = (y[e] - mu)*rstd*lw[layer*6 + e] + lb[layer*6 + e];
}

// -------------------------------- FF ----------------------------------------
// grid 512 = 128 token-tiles(128 tok) * 4 hidden-slices(512 j); 256 threads.
// thread: 2 tokens x 128 j; in-wave shuffle reduce over 4 sub-slices.
__global__ __launch_bounds__(256) void ff_kernel(
  const float* __restrict__ seq_in, const float* __restrict__ fcc,
  float* __restrict__ ffp, int layer)
{
  __shared__ float wc[512][16]; // 32 KB
  const int tid = threadIdx.x;
  const int tile  = blockIdx.x >> 2;
  const int slice = blockIdx.x & 3;
  const float* FC = fcc + (size_t)(layer*2048 + slice*512)*16;
  for (int i = tid; i < 2048; i += 256)
    ((float4*)wc)[i] = ((const float4*)FC)[i];

  const int wv = tid >> 6, lane = tid & 63, tp = lane >> 2, ss = lane & 3;
  const int tokA = tile*128 + wv*32 + tp*2;
  float sA[6], sB[6];
  #pragma unroll
  for (int e = 0; e < 6; e++){
    sA[e] = seq_in[tokA*6 + e];
    sB[e] = seq_in[(tokA+1)*6 + e];
  }
  float accA[6] = {0,0,0,0,0,0}, accB[6] = {0,0,0,0,0,0};
  __syncthreads();

  const int j0 = ss * 128;
  for (int jj = 0; jj < 128; jj++){
    const int j = j0 + ((jj + 31*ss) & 127); // stagger sub-slices across banks
    float4 wa = *(const float4*)&wc[j][0];
    float4 wb = *(const float4*)&wc[j][4];   // wb.z = f1 bias
    float4 w2a = *(const float4*)&wc[j][8];
    float4 w2b = *(const float4*)&wc[j][12]; // .x,.y = f2w[4],[5]
    float hA = fmaf(sA[5], wb.y, fmaf(sA[4], wb.x, fmaf(sA[3], wa.w,
               fmaf(sA[2], wa.z, fmaf(sA[1], wa.y, fmaf(sA[0], wa.x, wb.z))))));
    float hB = fmaf(sB[5], wb.y, fmaf(sB[4], wb.x, fmaf(sB[3], wa.w,
               fmaf(sB[2], wa.z, fmaf(sB[1], wa.y, fmaf(sB[0], wa.x, wb.z))))));
    hA = relu_(hA); hB = relu_(hB);
    accA[0] = fmaf(hA, w2a.x, accA[0]); accA[1] = fmaf(hA, w2a.y, accA[1]);
    accA[2] = fmaf(hA, w2a.z, accA[2]); accA[3] = fmaf(hA, w2a.w, accA[3]);
    accA[4] = fmaf(hA, w2b.x, accA[4]); accA[5] = fmaf(hA, w2b.y, accA[5]);
    accB[0] = fmaf(hB, w2a.x, accB[0]); accB[1] = fmaf(hB, w2a.y, accB[1]);
    accB[2] = fmaf(hB, w2a.z, accB[2]); accB[3] = fmaf(hB, w2a.w, accB[3]);
    accB[4] = fmaf(hB, w2b.x, accB[4]); accB[5] = fmaf(hB, w2b.y, accB[5]);
  }
  #pragma unroll
  for (int e = 0; e < 6; e++){
    accA[e] += __shfl_xor(accA[e], 1); accA[e] += __shfl_xor(accA[e], 2);
    accB[e] += __shfl_xor(accB[e], 1); accB[e] += __shfl_xor(accB[e], 2);
  }
  if (ss == 0){
    float* pa = ffp + (size_t)(slice*16384 + tokA)*6;
    #pragma unroll
    for (int e = 0; e < 6; e++){ pa[e] = accA[e]; pa[6 + e] = accB[e]; }
  }
}

// ---------------------------- FF-sum + LN ------------------------------------
__global__ __launch_bounds__(128) void ffln_kernel(
  const float* __restrict__ seq_in, const float* __restrict__ ffp,
  const float* __restrict__ f2b, const float* __restrict__ lw,
  const float* __restrict__ lb, float* __restrict__ seq_out, int layer)
{
  const int tok = blockIdx.x*128 + threadIdx.x;
  float y[6]; float mu = 0.f;
  #pragma unroll
  for (int e = 0; e < 6; e++){
    float v = seq_in[tok*6 + e] + f2b[layer*6 + e];
    v += ffp[(size_t)(0*16384 + tok)*6 + e];
    v += ffp[(size_t)(1*16384 + tok)*6 + e];
    v += ffp[(size_t)(2*16384 + tok)*6 + e];
    v += ffp[(size_t)(3*16384 + tok)*6 + e];
    y[e] = v; mu += v;
  }
  mu *= (1.f/6.f);
  float var = 0.f;
  #pragma unroll
  for (int e = 0; e < 6; e++){ float d = y[e] - mu; var = fmaf(d, d, var); }
  var *= (1.f/6.f);
  float rstd = rsqrtf(var + 1e-5f);
  #pragma unroll
  for (int e = 0; e < 6; e++)
    seq_out[tok*6 + e] = (y[e] - mu)*rstd*lw[layer*6 + e] + lb[layer*6 + e];
}

// ------------------------------- head ----------------------------------------
__global__ __launch_bounds__(192) void final_kernel(
  const float* __restrict__ seq, const float* __restrict__ o1w,
  const float* __restrict__ o1b, const float* __restrict__ o2w,
  float* __restrict__ out)
{
  __shared__ float red[6][33];
  __shared__ float pooled[6];
  const int n = blockIdx.x, tid = threadIdx.x, e = tid >> 5, ch = tid & 31;
  float s = 0.f;
  for (int i = ch; i < 1024; i += 32) s += seq[(n*SL + i)*ED + e];
  red[e][ch] = s;
  __syncthreads();
  if (tid < 6){
    float t = 0.f;
    for (int i = 0; i < 32; i++) t += red[tid][i];
    pooled[tid] = fmaxf(t * (1.f/1024.f), 0.f);
  }
  __syncthreads();
  if (tid == 0){
    float o1[7];
    #pragma unroll
    for (int o = 0; o < 7; o++){
      float a = o1b[o];
      #pragma unroll
      for (int e2 = 0; e2 < 6; e2++) a = fmaf(pooled[e2], o1w[o*6 + e2], a);
      o1[o] = relu_(a);
    }
    float lg[4];
    #pragma unroll
    for (int c = 0; c < 4; c++){
      float a = 0.f;
      #pragma unroll
      for (int o = 0; o < 7; o++) a = fmaf(o1[o], o2w[c*7 + o], a);
      lg[c] = a;
    }
    float m = fmaxf(fmaxf(lg[0], lg[1]), fmaxf(lg[2], lg[3]));
    float sum = 0.f;
    #pragma unroll
    for (int c = 0; c < 4; c++) sum += expf(lg[c] - m);
    float lse = m + logf(sum);
    #pragma unroll
    for (int c = 0; c < 4; c++) out[n*4 + c] = lg[c] - lse;
  }
}

// ------------------------------- launch --------------------------------------
extern "C" void kernel_launch(void* const* d_in, const int* in_sizes, int n_in,
                              void* d_out, int out_size, void* d_ws, size_t ws_size,
                              hipStream_t stream)
{
  const float* x    = (const float*)d_in[0];
  const float* k64  = (const float*)d_in[1];
  const float* b64  = (const float*)d_in[2];
  const float* k16  = (const float*)d_in[3];
  const float* b16  = (const float*)d_in[4];
  const float* k8   = (const float*)d_in[5];
  const float* b8   = (const float*)d_in[6];
  const float* kw3  = (const float*)d_in[7];
  const float* bw3  = (const float*)d_in[8];
  const float* km3  = (const float*)d_in[9];
  const float* bm3  = (const float*)d_in[10];
  const float* kn3  = (const float*)d_in[11];
  const float* bn3  = (const float*)d_in[12];
  const float* fc1w = (const float*)d_in[13];
  const float* fc1b = (const float*)d_in[14];
  const float* fc2w = (const float*)d_in[15];
  const float* fc2b = (const float*)d_in[16];
  const float* inw  = (const float*)d_in[17];
  const float* inb  = (const float*)d_in[18];
  const float* ow   = (const float*)d_in[19];
  const float* ob   = (const float*)d_in[20];
  const float* l1w  = (const float*)d_in[21];
  const float* l1b  = (const float*)d_in[22];
  const float* l2w  = (const float*)d_in[23];
  const float* l2b  = (const float*)d_in[24];
  const float* f1w  = (const float*)d_in[25];
  const float* f1b  = (const float*)d_in[26];
  const float* f2w  = (const float*)d_in[27];
  const float* f2b  = (const float*)d_in[28];
  const float* o1w  = (const float*)d_in[29];
  const float* o1b  = (const float*)d_in[30];
  const float* o2w  = (const float*)d_in[31];
  float* out = (float*)d_out;

  float* w = (float*)d_ws;
  float* seq_a = w;                  // 98304
  float* seq_b = w + 98304;          // 98304
  float* att   = w + 196608;         // 98304
  float* ffp   = w + 294912;         // 4*98304 = 393216
  float* k64r  = w + 688128;         // 1536
  float* fcc   = w + 689664;         // 65536
  // total 755200 floats ~= 3.0 MB

  prep_kernel<<<64, 256, 0, stream>>>(k64, f1w, f1b, f2w, k64r, fcc);
  frontend_kernel<<<256, 192, 0, stream>>>(x, k64r, b64, k16, b16, k8, b8,
      kw3, bw3, km3, bm3, kn3, bn3, fc1w, fc1b, fc2w, fc2b, seq_a);
  for (int l = 0; l < 2; l++){
    attn_kernel<<<768, 128, 0, stream>>>(seq_a, inw, inb, att, l);
    oproj_ln_kernel<<<128, 128, 0, stream>>>(seq_a, att, ow, ob, l1w, l1b, seq_b, l);
    ff_kernel<<<512, 256, 0, stream>>>(seq_b, fcc, ffp, l);
    ffln_kernel<<<128, 128, 0, stream>>>(seq_b, ffp, f2b, l2w, l2b, seq_a, l);
  }
  final_kernel<<<16, 192, 0, stream>>>(seq_a, o1w, o1b, o2w, out);
}